// Round 1
// baseline (1884.485 us; speedup 1.0000x reference)
//
#include <hip/hip_runtime.h>
#include <hip/hip_fp16.h>

#define N_B 8
#define P 2048
#define NP (N_B * P)          // 16384
#define EPS 0.1f
#define IEPS 10.0f            // 1/eps
#define LOG_EPS 1e-8f
#define MAX_ITER 50

// ---------------------------------------------------------------------------
// init: s0 = nu + LOG_EPS  (so a = nu'/s0 == 1, i.e. v=0), zero cost slots
// ---------------------------------------------------------------------------
__global__ __launch_bounds__(256) void k_init(const float* __restrict__ nu,
                                              float* __restrict__ s0,
                                              float* __restrict__ cost) {
    int idx = blockIdx.x * 256 + threadIdx.x;   // grid = NP/256 = 64 blocks
    s0[idx] = nu[idx] + LOG_EPS;
    if (idx < N_B) cost[idx] = 0.f;
}

// ---------------------------------------------------------------------------
// build K = exp(-C/eps) in fp16 (L3-resident working set: 67 MB)
// ---------------------------------------------------------------------------
__global__ __launch_bounds__(256) void k_build(const float* __restrict__ C,
                                               __half* __restrict__ K) {
    size_t idx = ((size_t)blockIdx.x * 256 + threadIdx.x) * 4;  // grid*256*4 == N*P*P
    float4 c = *(const float4*)(C + idx);
    __half2 h01 = __floats2half2_rn(expf(-IEPS * c.x), expf(-IEPS * c.y));
    __half2 h23 = __floats2half2_rn(expf(-IEPS * c.z), expf(-IEPS * c.w));
    *(__half2*)(K + idx)     = h01;
    *(__half2*)(K + idx + 2) = h23;
}

// ---------------------------------------------------------------------------
// row pass: w_i = mu'_i / sum_j K_ij * a_j,  a_j = nu'_j / sA_j (staged in LDS)
// Also zeroes sB (the next col-pass accumulator) using the first 64 blocks.
// 8 rows per block; each of the 4 waves owns 2 rows -> wave-local reduction only.
// ---------------------------------------------------------------------------
template <bool USEK>
__global__ __launch_bounds__(256) void k_row(const __half* __restrict__ K,
                                             const float* __restrict__ C,
                                             const float* __restrict__ mu,
                                             const float* __restrict__ nu,
                                             const float* __restrict__ sA,
                                             float* __restrict__ sB,
                                             float* __restrict__ w) {
    __shared__ float a_sh[P];
    const int tid = threadIdx.x;
    if (blockIdx.x < NP / 256) sB[blockIdx.x * 256 + tid] = 0.f;

    const int n  = blockIdx.x >> 8;          // 256 blocks per batch (P/8)
    const int r0 = (blockIdx.x & 255) * 8;
    const float* sAn = sA + n * P;
    const float* nun = nu + n * P;
    for (int j = tid; j < P; j += 256)
        a_sh[j] = (nun[j] + LOG_EPS) / sAn[j];
    __syncthreads();

    const int wave = tid >> 6, lane = tid & 63;
    for (int rr = wave; rr < 8; rr += 4) {
        const int i = r0 + rr;
        const size_t rowoff = (size_t)(n * P + i) * P;
        float sum = 0.f;
        #pragma unroll
        for (int jj = 0; jj < P; jj += 256) {
            const int j = jj + lane * 4;
            float4 av = *(const float4*)&a_sh[j];
            float k0, k1, k2, k3;
            if (USEK) {
                const __half2* kp = (const __half2*)(K + rowoff + j);
                float2 f01 = __half22float2(kp[0]);
                float2 f23 = __half22float2(kp[1]);
                k0 = f01.x; k1 = f01.y; k2 = f23.x; k3 = f23.y;
            } else {
                float4 c4 = *(const float4*)(C + rowoff + j);
                k0 = expf(-IEPS * c4.x); k1 = expf(-IEPS * c4.y);
                k2 = expf(-IEPS * c4.z); k3 = expf(-IEPS * c4.w);
            }
            sum += k0 * av.x + k1 * av.y + k2 * av.z + k3 * av.w;
        }
        #pragma unroll
        for (int off = 32; off > 0; off >>= 1) sum += __shfl_down(sum, off, 64);
        if (lane == 0) w[n * P + i] = (mu[n * P + i] + LOG_EPS) / sum;
    }
}

// ---------------------------------------------------------------------------
// col pass: sB_j += sum_i K_ij * w_i  (partial over 64-row chunks, atomicAdd)
// grid = n(8) x jt(4) x rc(32) = 1024 blocks; 2 adjacent cols per thread.
// ---------------------------------------------------------------------------
template <bool USEK>
__global__ __launch_bounds__(256) void k_col(const __half* __restrict__ K,
                                             const float* __restrict__ C,
                                             const float* __restrict__ w,
                                             float* __restrict__ sB) {
    const int RPB = 64;
    int b = blockIdx.x;
    const int rc = b & 31; b >>= 5;
    const int jt = b & 3;  b >>= 2;
    const int n  = b;
    const int j  = jt * 512 + threadIdx.x * 2;
    const int i0 = rc * RPB;
    const float* wn = w + n * P;
    float s0 = 0.f, s1 = 0.f;
    if (USEK) {
        const __half2* kp = (const __half2*)(K + ((size_t)n * P + i0) * P + j);
        #pragma unroll 4
        for (int i = 0; i < RPB; ++i) {
            const float wi = wn[i0 + i];
            float2 kv = __half22float2(*kp);
            s0 += wi * kv.x; s1 += wi * kv.y;
            kp += P / 2;
        }
    } else {
        const float* cp = C + ((size_t)n * P + i0) * P + j;
        #pragma unroll 2
        for (int i = 0; i < RPB; ++i) {
            const float wi = wn[i0 + i];
            s0 += wi * expf(-IEPS * cp[0]);
            s1 += wi * expf(-IEPS * cp[1]);
            cp += P;
        }
    }
    atomicAdd(&sB[n * P + j],     s0);
    atomicAdd(&sB[n * P + j + 1], s1);
}

// ---------------------------------------------------------------------------
// final: pi = w_i * a_j * exp(-C/eps) (fp32 C), write pi + C copy, reduce cost
// ---------------------------------------------------------------------------
__global__ __launch_bounds__(256) void k_final(const float* __restrict__ C,
                                               const float* __restrict__ nu,
                                               const float* __restrict__ w,
                                               const float* __restrict__ sA,
                                               float* __restrict__ out) {
    const int g   = blockIdx.x;              // NP blocks, one row each
    const int n   = g >> 11;
    const int tid = threadIdx.x;
    const float wi = w[g];
    const size_t rowoff = (size_t)g * P;
    const float* Crow = C + rowoff;
    float* pi_out = out + N_B + rowoff;
    float* c_out  = out + N_B + (size_t)NP * P + rowoff;
    const float* sn  = sA + n * P;
    const float* nun = nu + n * P;
    float cost = 0.f;
    #pragma unroll
    for (int jj = 0; jj < P; jj += 1024) {
        const int j = jj + tid * 4;
        float4 c4 = *(const float4*)(Crow + j);
        float a0 = (nun[j    ] + LOG_EPS) / sn[j    ];
        float a1 = (nun[j + 1] + LOG_EPS) / sn[j + 1];
        float a2 = (nun[j + 2] + LOG_EPS) / sn[j + 2];
        float a3 = (nun[j + 3] + LOG_EPS) / sn[j + 3];
        float4 p;
        p.x = wi * a0 * expf(-IEPS * c4.x);
        p.y = wi * a1 * expf(-IEPS * c4.y);
        p.z = wi * a2 * expf(-IEPS * c4.z);
        p.w = wi * a3 * expf(-IEPS * c4.w);
        *(float4*)(pi_out + j) = p;
        *(float4*)(c_out + j)  = c4;
        cost += p.x * c4.x + p.y * c4.y + p.z * c4.z + p.w * c4.w;
    }
    const int wave = tid >> 6, lane = tid & 63;
    #pragma unroll
    for (int off = 32; off > 0; off >>= 1) cost += __shfl_down(cost, off, 64);
    __shared__ float red[4];
    if (lane == 0) red[wave] = cost;
    __syncthreads();
    if (tid == 0) atomicAdd(&out[n], red[0] + red[1] + red[2] + red[3]);
}

// ---------------------------------------------------------------------------
extern "C" void kernel_launch(void* const* d_in, const int* in_sizes, int n_in,
                              void* d_out, int out_size, void* d_ws, size_t ws_size,
                              hipStream_t stream) {
    const float* C  = (const float*)d_in[0];
    const float* mu = (const float*)d_in[1];
    const float* nu = (const float*)d_in[2];
    float* out = (float*)d_out;

    // ws layout: s0[NP] | s1[NP] | w[NP] | K[N*P*P] (fp16)
    float* s0 = (float*)d_ws;
    float* s1 = s0 + NP;
    float* w  = s1 + NP;
    __half* K = (__half*)(w + NP);
    const size_t needK = 3ull * NP * sizeof(float) + (size_t)NP * P * sizeof(__half);
    const bool useK = (ws_size >= needK);

    k_init<<<NP / 256, 256, 0, stream>>>(nu, s0, out);
    if (useK) k_build<<<((size_t)NP * P) / 1024, 256, 0, stream>>>(C, K);

    for (int t = 0; t < MAX_ITER; ++t) {
        float* sA = (t & 1) ? s1 : s0;
        float* sB = (t & 1) ? s0 : s1;
        if (useK) {
            k_row<true><<<NP / 8, 256, 0, stream>>>(K, C, mu, nu, sA, sB, w);
            k_col<true><<<8 * 4 * 32, 256, 0, stream>>>(K, C, w, sB);
        } else {
            k_row<false><<<NP / 8, 256, 0, stream>>>(K, C, mu, nu, sA, sB, w);
            k_col<false><<<8 * 4 * 32, 256, 0, stream>>>(K, C, w, sB);
        }
    }
    // last col pass (t=49, odd) wrote s0 -> final a comes from s0
    k_final<<<NP, 256, 0, stream>>>(C, nu, w, s0, out);
}